// Round 4
// baseline (87.548 us; speedup 1.0000x reference)
//
#include <hip/hip_runtime.h>
#include <math.h>

// Problem constants (from the JAX reference)
#define IMG    14
#define HW     196       // 14*14 spatial positions
#define DEPTH  512       // channels C
#define NB     512       // batch
#define NSEG   28        // spatial segments per block
#define RPT    7         // rows (positions) per thread = 196/28
#define GPR    16        // f32x4 channel groups per row (CTILE/4)
#define CTILE  64        // channels per block

typedef float f32x4 __attribute__((ext_vector_type(4)));
typedef int   i32x4 __attribute__((ext_vector_type(4)));

// Block: 448 threads = 7 waves. Thread (g, q): g = f32x4 channel group
// (16 B -> global_load_dwordx4), q = spatial segment of 7 consecutive rows.
// Per-thread live data: 7 x f32x4 = 28 floats -> fits VGPR comfortably.
// Grid: 512 b x 8 ctiles = 4096 blocks; LDS 14 KB -> 4 blocks/CU (wave-capped).
__global__ __launch_bounds__(448) void mask_kernel(const float* __restrict__ x,
                                                   float* __restrict__ out) {
    const int tid = threadIdx.x;
    const int g   = tid & 15;     // channel group within tile
    const int q   = tid >> 4;     // spatial segment, 0..27
    const int b   = blockIdx.x >> 3;
    const int ct  = blockIdx.x & 7;
    const int c0  = ct * CTILE + (g << 2);

    // base float offset of (b, s = q*7, c0)
    const size_t base = ((size_t)b * HW + (size_t)q * RPT) * DEPTH + (size_t)c0;
    const float* px = x + base;
    float*       po = out + base;

    // ---- Phase 1: 7 x dwordx4 loads into registers ----
    f32x4 v[RPT];
#pragma unroll
    for (int k = 0; k < RPT; ++k) {
        v[k] = *(const f32x4*)(px + (size_t)k * DEPTH);
    }

    // per-component streaming argmax (ascending k, strict > = first occurrence)
    float b0 = -INFINITY, b1 = -INFINITY, b2 = -INFINITY, b3 = -INFINITY;
    int   i0 = 0, i1 = 0, i2 = 0, i3 = 0;
#pragma unroll
    for (int k = 0; k < RPT; ++k) {
        const int s = q * RPT + k;
        if (v[k].x > b0) { b0 = v[k].x; i0 = s; }
        if (v[k].y > b1) { b1 = v[k].y; i1 = s; }
        if (v[k].z > b2) { b2 = v[k].z; i2 = s; }
        if (v[k].w > b3) { b3 = v[k].w; i3 = s; }
    }

    // pin the 28 loaded floats in registers (block load rematerialization;
    // small enough that the compiler keeps them resident instead of spilling)
#pragma unroll
    for (int k = 0; k < RPT; ++k) {
        float a0 = v[k].x, a1 = v[k].y, a2 = v[k].z, a3 = v[k].w;
        asm volatile("" : "+v"(a0), "+v"(a1), "+v"(a2), "+v"(a3));
        v[k].x = a0; v[k].y = a1; v[k].z = a2; v[k].w = a3;
    }

    // ---- Cross-segment argmax reduction via LDS (14 KB) ----
    __shared__ f32x4 smax[NSEG][GPR];
    __shared__ i32x4 sidx[NSEG][GPR];
    smax[q][g] = (f32x4){b0, b1, b2, b3};
    sidx[q][g] = (i32x4){i0, i1, i2, i3};
    __syncthreads();

    f32x4 m  = smax[0][g];
    i32x4 mi = sidx[0][g];
#pragma unroll
    for (int r = 1; r < NSEG; ++r) {
        // ascending segment order + strict > keeps the first occurrence,
        // matching jnp.argmax tie semantics
        const f32x4 vv = smax[r][g];
        const i32x4 ii = sidx[r][g];
        if (vv.x > m.x) { m.x = vv.x; mi.x = ii.x; }
        if (vv.y > m.y) { m.y = vv.y; mi.y = ii.y; }
        if (vv.z > m.z) { m.z = vv.z; mi.z = ii.z; }
        if (vv.w > m.w) { m.w = vv.w; mi.w = ii.w; }
    }

    const float fi0 = (float)(mi.x / IMG), fj0 = (float)(mi.x % IMG);
    const float fi1 = (float)(mi.y / IMG), fj1 = (float)(mi.y % IMG);
    const float fi2 = (float)(mi.z / IMG), fj2 = (float)(mi.z % IMG);
    const float fi3 = (float)(mi.w / IMG), fj3 = (float)(mi.w % IMG);
    const float TAU = (float)(0.5 / 196.0);

    // s = 7q + k  =>  si = q>>1 (constant per thread), sj = 7*(q&1) + k
    const float fsi = (float)(q >> 1);
    const int   sj0 = 7 * (q & 1);

    // ---- Phase 2: mask register-held values, store (no global re-read) ----
#pragma unroll
    for (int k = 0; k < RPT; ++k) {
        const float fsj = (float)(sj0 + k);
        f32x4 o;
        {
            const float dist = fabsf(fsi - fi0) + fabsf(fsj - fj0);
            o.x = v[k].x * (TAU * fmaxf(1.0f - (4.0f * dist) / 14.0f, -1.0f));
        }
        {
            const float dist = fabsf(fsi - fi1) + fabsf(fsj - fj1);
            o.y = v[k].y * (TAU * fmaxf(1.0f - (4.0f * dist) / 14.0f, -1.0f));
        }
        {
            const float dist = fabsf(fsi - fi2) + fabsf(fsj - fj2);
            o.z = v[k].z * (TAU * fmaxf(1.0f - (4.0f * dist) / 14.0f, -1.0f));
        }
        {
            const float dist = fabsf(fsi - fi3) + fabsf(fsj - fj3);
            o.w = v[k].w * (TAU * fmaxf(1.0f - (4.0f * dist) / 14.0f, -1.0f));
        }
        *(f32x4*)(po + (size_t)k * DEPTH) = o;
    }
}

extern "C" void kernel_launch(void* const* d_in, const int* in_sizes, int n_in,
                              void* d_out, int out_size, void* d_ws, size_t ws_size,
                              hipStream_t stream) {
    (void)in_sizes; (void)n_in; (void)out_size; (void)d_ws; (void)ws_size;
    const float* x = (const float*)d_in[0];
    float* out = (float*)d_out;
    dim3 grid(NB * (DEPTH / CTILE));  // 4096
    dim3 block(448);
    hipLaunchKernelGGL(mask_kernel, grid, block, 0, stream, x, out);
}